// Round 5
// baseline (301.088 us; speedup 1.0000x reference)
//
#include <hip/hip_runtime.h>
#include <cstdint>
#include <cstddef>
#include <math.h>

typedef unsigned long long u64;

#define BB 4
#define NN 32768
#define DD 512
#define KK 8192
#define TILE 8192
#define LT 1024      // threads per sort/merge block
#define VE 8         // elements per thread (TILE / LT)
#define RPW 8        // score: rows per wave
#define RPG 4        // gather: rows per wave

// DIAGNOSTIC ROUND: score and gather repeated SREP/GREP times (identical
// result each rep; memory clobber defeats CSE/DSE) so their dispatches
// exceed the ~150us harness fill ops and appear in the top-5 counter rows.
#define SREP 4
#define GREP 8

// ---------------- score kernel: RPW rows per wave ----------------
__global__ __launch_bounds__(256) void score_kernel(const float* __restrict__ h,
                                                    const float* __restrict__ sf,
                                                    u64* __restrict__ keys) {
    int wave = (blockIdx.x * 256 + threadIdx.x) >> 6;  // 0..16383
    int lane = threadIdx.x & 63;
    int b  = wave >> 12;                 // 4096 waves per batch
    int n0 = (wave & 4095) * RPW;        // first row of this wave's group
    for (int rep = 0; rep < SREP; ++rep) {
        const float4* s4 = (const float4*)(sf) + (size_t)b * 128;
        float4 w0 = s4[lane], w1 = s4[lane + 64];
        const float4* hb = (const float4*)(h) + ((size_t)b * NN + n0) * 128;
        float4 r0[RPW], r1[RPW];
#pragma unroll
        for (int r = 0; r < RPW; ++r) {  // issue all 16 loads before any use
            r0[r] = hb[r * 128 + lane];
            r1[r] = hb[r * 128 + 64 + lane];
        }
        u64 mykey = 0;
#pragma unroll
        for (int r = 0; r < RPW; ++r) {
            double acc = (double)r0[r].x * w0.x + (double)r0[r].y * w0.y +
                         (double)r0[r].z * w0.z + (double)r0[r].w * w0.w +
                         (double)r1[r].x * w1.x + (double)r1[r].y * w1.y +
                         (double)r1[r].z * w1.z + (double)r1[r].w * w1.w;
#pragma unroll
            for (int off = 32; off >= 1; off >>= 1)
                acc += __shfl_xor(acc, off, 64);
            // f32 sigmoid pipeline — replicates the reference's tie-bucket
            // structure near saturation (validated round 2; do not change).
            float x = (float)acc;
            float e = expf(-x);
            float s = 1.0f / (1.0f + e);
            unsigned sb = __float_as_uint(s);
            u64 key = ((u64)(~sb) << 32) | (unsigned)(n0 + r);
            if (lane == r) mykey = key;  // lane r keeps row r's key
        }
        if (lane < RPW)                  // one coalesced 64 B store
            keys[((size_t)b << 15) + n0 + lane] = mykey;
        asm volatile("" ::: "memory");   // rep fence: no CSE/DSE across reps
    }
}

// ---------------- register-resident bitonic primitives ----------------
__device__ __forceinline__ void reg_pass(u64 v[VE], int base, int stage, int j) {
#pragma unroll
    for (int e = 0; e < VE; ++e) {
        if ((e & j) == 0) {
            int f = e | j;
            bool up = (((base + e) & stage) == 0);
            u64 a = v[e], b = v[f];
            bool sw = up ? (a > b) : (a < b);
            if (sw) { v[e] = b; v[f] = a; }
        }
    }
}

__device__ __forceinline__ void shfl_pass(u64 v[VE], int t, int base, int stage, int j) {
    int m = j >> 3;                       // lane xor mask (VE==8)
    bool lower = ((t & m) == 0);
#pragma unroll
    for (int e = 0; e < VE; ++e) {
        u64 pv = __shfl_xor(v[e], m, 64);
        bool up = (((base + e) & stage) == 0);
        bool tm = (lower == up);
        bool lt = v[e] < pv;
        v[e] = (tm == lt) ? v[e] : pv;
    }
}

__device__ __forceinline__ void lds_pass(u64 v[VE], unsigned* lo, unsigned* hi,
                                         int t, int base, int stage, int j) {
    __syncthreads();                      // protect WAR vs previous pass's reads
#pragma unroll
    for (int e = 0; e < VE; ++e) {
        lo[e * LT + t] = (unsigned)v[e];
        hi[e * LT + t] = (unsigned)(v[e] >> 32);
    }
    __syncthreads();
    int pt = t ^ (j >> 3);
    bool lower = ((t & (j >> 3)) == 0);
#pragma unroll
    for (int e = 0; e < VE; ++e) {
        u64 pv = ((u64)hi[e * LT + pt] << 32) | (u64)lo[e * LT + pt];
        bool up = (((base + e) & stage) == 0);
        bool tm = (lower == up);
        bool lt = v[e] < pv;
        v[e] = (tm == lt) ? v[e] : pv;
    }
}

// ------------- local full ascending sort of one 8192-tile -------------
__global__ __launch_bounds__(LT) void local_sort_kernel(u64* __restrict__ keys) {
    __shared__ unsigned lds_lo[TILE];
    __shared__ unsigned lds_hi[TILE];
    int b = blockIdx.x >> 2;
    int tile = blockIdx.x & 3;
    u64* kb = keys + ((size_t)b << 15) + tile * TILE;
    int t = threadIdx.x;
    int base = t * VE;
    u64 v[VE];
#pragma unroll
    for (int q = 0; q < VE / 2; ++q) {
        ulonglong2 p = ((const ulonglong2*)(kb + base))[q];
        v[2 * q] = p.x; v[2 * q + 1] = p.y;
    }
    for (int stage = 2; stage <= TILE; stage <<= 1) {
        int j = stage >> 1;
        for (; j >= 512; j >>= 1) lds_pass(v, lds_lo, lds_hi, t, base, stage, j);
        for (; j >= 8; j >>= 1)   shfl_pass(v, t, base, stage, j);
        for (; j >= 1; j >>= 1)   reg_pass(v, base, stage, j);
    }
#pragma unroll
    for (int q = 0; q < VE / 2; ++q) {
        ulonglong2 p; p.x = v[2 * q]; p.y = v[2 * q + 1];
        ((ulonglong2*)(kb + base))[q] = p;
    }
}

// ------------- top-8192 merge of two ascending 8192 runs, in-place into A -------------
__global__ __launch_bounds__(LT) void merge_topk_kernel(u64* __restrict__ keys,
                                                        int pshift, int boff) {
    __shared__ unsigned lds_lo[TILE];
    __shared__ unsigned lds_hi[TILE];
    int b = blockIdx.x >> pshift;
    int p = blockIdx.x & ((1 << pshift) - 1);
    u64* A = keys + ((size_t)b << 15) + (size_t)p * 2 * boff;
    u64* B = A + boff;
    int t = threadIdx.x;
    int base = t * VE;
    u64 a[VE], rb[VE], v[VE];
#pragma unroll
    for (int q = 0; q < VE / 2; ++q) {
        ulonglong2 pa = ((const ulonglong2*)(A + base))[q];
        a[2 * q] = pa.x; a[2 * q + 1] = pa.y;
        ulonglong2 pb = ((const ulonglong2*)(B + (TILE - VE - base)))[q];
        rb[2 * q] = pb.x; rb[2 * q + 1] = pb.y;
    }
#pragma unroll
    for (int e = 0; e < VE; ++e) {
        u64 x = a[e], y = rb[VE - 1 - e];       // y = B[TILE-1-(base+e)]
        v[e] = x < y ? x : y;
    }
    const int stage = 2 * TILE;                  // up == true everywhere
    int j = TILE >> 1;
    for (; j >= 512; j >>= 1) lds_pass(v, lds_lo, lds_hi, t, base, stage, j);
    for (; j >= 8; j >>= 1)   shfl_pass(v, t, base, stage, j);
    for (; j >= 1; j >>= 1)   reg_pass(v, base, stage, j);
#pragma unroll
    for (int q = 0; q < VE / 2; ++q) {
        ulonglong2 pv; pv.x = v[2 * q]; pv.y = v[2 * q + 1];
        ((ulonglong2*)(A + base))[q] = pv;
    }
}

// ---------------- gather + scale: RPG rows per wave ----------------
__global__ __launch_bounds__(256) void gather_kernel(const float* __restrict__ h,
                                                     const u64* __restrict__ keys,
                                                     float* __restrict__ out) {
    int wave = (blockIdx.x * 256 + threadIdx.x) >> 6;  // 0..8191
    int lane = threadIdx.x & 63;
    int b  = wave >> 11;                 // 2048 waves per batch
    int j0 = (wave & 2047) * RPG;
    for (int rep = 0; rep < GREP; ++rep) {
        u64 k[RPG];
#pragma unroll
        for (int r = 0; r < RPG; ++r)
            k[r] = keys[((size_t)b << 15) + j0 + r];
        float4 x0[RPG], x1[RPG];
        const float4* srcp[RPG];
#pragma unroll
        for (int r = 0; r < RPG; ++r) {  // issue all 8 loads before any use
            int idx = (int)(unsigned)(k[r] & 0xFFFFFFFFu);
            srcp[r] = (const float4*)(h) + ((size_t)b * NN + idx) * 128;
            x0[r] = srcp[r][lane];
            x1[r] = srcp[r][lane + 64];
        }
#pragma unroll
        for (int r = 0; r < RPG; ++r) {
            float v = __uint_as_float(~(unsigned)(k[r] >> 32));
            float4* dst = (float4*)(out) + ((size_t)b * KK + j0 + r) * 128;
            float4 a = x0[r], c = x1[r];
            a.x *= v; a.y *= v; a.z *= v; a.w *= v;
            c.x *= v; c.y *= v; c.z *= v; c.w *= v;
            dst[lane] = a;
            dst[lane + 64] = c;
        }
        asm volatile("" ::: "memory");   // rep fence: no CSE/DSE across reps
    }
}

extern "C" void kernel_launch(void* const* d_in, const int* in_sizes, int n_in,
                              void* d_out, int out_size, void* d_ws, size_t ws_size,
                              hipStream_t stream) {
    const float* h  = (const float*)d_in[0];
    const float* sf = (const float*)d_in[1];
    float* out = (float*)d_out;
    u64* keys = (u64*)d_ws;    // 4*32768*8 = 1 MiB

    score_kernel<<<(BB * NN) / (RPW * 4), 256, 0, stream>>>(h, sf, keys);
    local_sort_kernel<<<BB * 4, LT, 0, stream>>>(keys);
    merge_topk_kernel<<<BB * 2, LT, 0, stream>>>(keys, 1, TILE);      // 4 runs -> 2
    merge_topk_kernel<<<BB * 1, LT, 0, stream>>>(keys, 0, 2 * TILE);  // 2 runs -> 1
    gather_kernel<<<(BB * KK) / (RPG * 4), 256, 0, stream>>>(h, keys, out);
}

// Round 6
// 142.648 us; speedup vs baseline: 2.1107x; 2.1107x over previous
//
#include <hip/hip_runtime.h>
#include <cstdint>
#include <cstddef>
#include <math.h>

typedef unsigned long long u64;

#define BB 4
#define NN 32768
#define DD 512
#define KK 8192
#define TILE 8192
#define LT 1024      // threads per sort/merge block
#define VE 8         // elements per thread (TILE / LT)
#define RPW 8        // score: rows per wave
#define RPG 4        // gather: rows per wave

// ---------------- score kernel: RPW rows per wave ----------------
__global__ __launch_bounds__(256) void score_kernel(const float* __restrict__ h,
                                                    const float* __restrict__ sf,
                                                    u64* __restrict__ keys) {
    int wave = (blockIdx.x * 256 + threadIdx.x) >> 6;  // 0..16383
    int lane = threadIdx.x & 63;
    int b  = wave >> 12;                 // 4096 waves per batch
    int n0 = (wave & 4095) * RPW;        // first row of this wave's group
    const float4* s4 = (const float4*)(sf) + (size_t)b * 128;
    float4 w0 = s4[lane], w1 = s4[lane + 64];
    const float4* hb = (const float4*)(h) + ((size_t)b * NN + n0) * 128;
    float4 r0[RPW], r1[RPW];
#pragma unroll
    for (int r = 0; r < RPW; ++r) {      // issue all 16 loads before any use
        r0[r] = hb[r * 128 + lane];
        r1[r] = hb[r * 128 + 64 + lane];
    }
    u64 mykey = 0;
#pragma unroll
    for (int r = 0; r < RPW; ++r) {
        double acc = (double)r0[r].x * w0.x + (double)r0[r].y * w0.y +
                     (double)r0[r].z * w0.z + (double)r0[r].w * w0.w +
                     (double)r1[r].x * w1.x + (double)r1[r].y * w1.y +
                     (double)r1[r].z * w1.z + (double)r1[r].w * w1.w;
#pragma unroll
        for (int off = 32; off >= 1; off >>= 1)
            acc += __shfl_xor(acc, off, 64);
        // f32 sigmoid pipeline — replicates the reference's tie-bucket
        // structure near saturation (validated round 2; do not change).
        float x = (float)acc;
        float e = expf(-x);
        float s = 1.0f / (1.0f + e);
        unsigned sb = __float_as_uint(s);
        u64 key = ((u64)(~sb) << 32) | (unsigned)(n0 + r);
        if (lane == r) mykey = key;      // lane r keeps row r's key
    }
    if (lane < RPW)                      // one coalesced 64 B store
        keys[((size_t)b << 15) + n0 + lane] = mykey;
}

// ---------------- register-resident bitonic primitives ----------------
// Element i = VE*t + e. CE rule: lower = ((i&j)==0), up = ((i&stage)==0);
// take-min iff (lower == up).
// RULE #20 FIX: J is a template (compile-time) constant so v[e|J] is a
// static register index — runtime J sent v[] to scratch (localMem).

template<int J>
__device__ __forceinline__ void reg_ce(u64 v[VE], int base, int stage) {
#pragma unroll
    for (int e = 0; e < VE; ++e) {
        if ((e & J) == 0) {
            const int f = e | J;                  // compile-time after unroll
            bool up = (((base + e) & stage) == 0);
            u64 a = v[e], b = v[f];
            bool sw = up ? (a > b) : (a < b);
            if (sw) { v[e] = b; v[f] = a; }
        }
    }
}

__device__ __forceinline__ void reg_tail(u64 v[VE], int base, int stage, int jmax) {
    // jmax = min(stage/2, 4); stage is runtime but only gates which CEs run
    if (jmax >= 4) reg_ce<4>(v, base, stage);
    if (jmax >= 2) reg_ce<2>(v, base, stage);
    reg_ce<1>(v, base, stage);
}

__device__ __forceinline__ void shfl_pass(u64 v[VE], int t, int base, int stage, int j) {
    int m = j >> 3;                       // lane xor mask (VE==8); runtime ok (no v[] index)
    bool lower = ((t & m) == 0);
#pragma unroll
    for (int e = 0; e < VE; ++e) {
        u64 pv = __shfl_xor(v[e], m, 64);
        bool up = (((base + e) & stage) == 0);
        bool tm = (lower == up);
        bool lt = v[e] < pv;
        v[e] = (tm == lt) ? v[e] : pv;
    }
}

__device__ __forceinline__ void lds_pass(u64 v[VE], unsigned* lo, unsigned* hi,
                                         int t, int base, int stage, int j) {
    __syncthreads();                      // protect WAR vs previous pass's reads
#pragma unroll
    for (int e = 0; e < VE; ++e) {
        lo[e * LT + t] = (unsigned)v[e];
        hi[e * LT + t] = (unsigned)(v[e] >> 32);
    }
    __syncthreads();
    int pt = t ^ (j >> 3);
    bool lower = ((t & (j >> 3)) == 0);
#pragma unroll
    for (int e = 0; e < VE; ++e) {
        u64 pv = ((u64)hi[e * LT + pt] << 32) | (u64)lo[e * LT + pt];
        bool up = (((base + e) & stage) == 0);
        bool tm = (lower == up);
        bool lt = v[e] < pv;
        v[e] = (tm == lt) ? v[e] : pv;
    }
}

// ------------- local full ascending sort of one 8192-tile -------------
__global__ __launch_bounds__(LT) void local_sort_kernel(u64* __restrict__ keys) {
    __shared__ unsigned lds_lo[TILE];
    __shared__ unsigned lds_hi[TILE];
    int b = blockIdx.x >> 2;
    int tile = blockIdx.x & 3;
    u64* kb = keys + ((size_t)b << 15) + tile * TILE;
    int t = threadIdx.x;
    int base = t * VE;
    u64 v[VE];
#pragma unroll
    for (int q = 0; q < VE / 2; ++q) {
        ulonglong2 p = ((const ulonglong2*)(kb + base))[q];
        v[2 * q] = p.x; v[2 * q + 1] = p.y;
    }
    for (int stage = 2; stage <= TILE; stage <<= 1) {
        int j = stage >> 1;
        for (; j >= 512; j >>= 1) lds_pass(v, lds_lo, lds_hi, t, base, stage, j);
        for (; j >= 8; j >>= 1)   shfl_pass(v, t, base, stage, j);
        reg_tail(v, base, stage, (stage >> 1) < 4 ? (stage >> 1) : 4);
    }
#pragma unroll
    for (int q = 0; q < VE / 2; ++q) {
        ulonglong2 p; p.x = v[2 * q]; p.y = v[2 * q + 1];
        ((ulonglong2*)(kb + base))[q] = p;
    }
}

// ------------- top-8192 merge of two ascending 8192 runs, in-place into A -------------
// C[i] = min(A[i], B[8191-i]) is bitonic and holds the 8192 smallest keys;
// a 13-pass ascending sweep sorts it.
__global__ __launch_bounds__(LT) void merge_topk_kernel(u64* __restrict__ keys,
                                                        int pshift, int boff) {
    __shared__ unsigned lds_lo[TILE];
    __shared__ unsigned lds_hi[TILE];
    int b = blockIdx.x >> pshift;
    int p = blockIdx.x & ((1 << pshift) - 1);
    u64* A = keys + ((size_t)b << 15) + (size_t)p * 2 * boff;
    u64* B = A + boff;
    int t = threadIdx.x;
    int base = t * VE;
    u64 a[VE], rb[VE], v[VE];
#pragma unroll
    for (int q = 0; q < VE / 2; ++q) {
        ulonglong2 pa = ((const ulonglong2*)(A + base))[q];
        a[2 * q] = pa.x; a[2 * q + 1] = pa.y;
        ulonglong2 pb = ((const ulonglong2*)(B + (TILE - VE - base)))[q];
        rb[2 * q] = pb.x; rb[2 * q + 1] = pb.y;
    }
#pragma unroll
    for (int e = 0; e < VE; ++e) {
        u64 x = a[e], y = rb[VE - 1 - e];       // y = B[TILE-1-(base+e)]
        v[e] = x < y ? x : y;
    }
    const int stage = 2 * TILE;                  // up == true everywhere
    int j = TILE >> 1;
    for (; j >= 512; j >>= 1) lds_pass(v, lds_lo, lds_hi, t, base, stage, j);
    for (; j >= 8; j >>= 1)   shfl_pass(v, t, base, stage, j);
    reg_tail(v, base, stage, 4);
#pragma unroll
    for (int q = 0; q < VE / 2; ++q) {
        ulonglong2 pv; pv.x = v[2 * q]; pv.y = v[2 * q + 1];
        ((ulonglong2*)(A + base))[q] = pv;
    }
}

// ---------------- gather + scale: RPG rows per wave ----------------
__global__ __launch_bounds__(256) void gather_kernel(const float* __restrict__ h,
                                                     const u64* __restrict__ keys,
                                                     float* __restrict__ out) {
    int wave = (blockIdx.x * 256 + threadIdx.x) >> 6;  // 0..8191
    int lane = threadIdx.x & 63;
    int b  = wave >> 11;                 // 2048 waves per batch
    int j0 = (wave & 2047) * RPG;
    u64 k[RPG];
#pragma unroll
    for (int r = 0; r < RPG; ++r)
        k[r] = keys[((size_t)b << 15) + j0 + r];
    float4 x0[RPG], x1[RPG];
    const float4* srcp[RPG];
#pragma unroll
    for (int r = 0; r < RPG; ++r) {      // issue all 8 loads before any use
        int idx = (int)(unsigned)(k[r] & 0xFFFFFFFFu);
        srcp[r] = (const float4*)(h) + ((size_t)b * NN + idx) * 128;
        x0[r] = srcp[r][lane];
        x1[r] = srcp[r][lane + 64];
    }
#pragma unroll
    for (int r = 0; r < RPG; ++r) {
        float v = __uint_as_float(~(unsigned)(k[r] >> 32));
        float4* dst = (float4*)(out) + ((size_t)b * KK + j0 + r) * 128;
        float4 a = x0[r], c = x1[r];
        a.x *= v; a.y *= v; a.z *= v; a.w *= v;
        c.x *= v; c.y *= v; c.z *= v; c.w *= v;
        dst[lane] = a;
        dst[lane + 64] = c;
    }
}

extern "C" void kernel_launch(void* const* d_in, const int* in_sizes, int n_in,
                              void* d_out, int out_size, void* d_ws, size_t ws_size,
                              hipStream_t stream) {
    const float* h  = (const float*)d_in[0];
    const float* sf = (const float*)d_in[1];
    float* out = (float*)d_out;
    u64* keys = (u64*)d_ws;    // 4*32768*8 = 1 MiB

    score_kernel<<<(BB * NN) / (RPW * 4), 256, 0, stream>>>(h, sf, keys);
    local_sort_kernel<<<BB * 4, LT, 0, stream>>>(keys);
    merge_topk_kernel<<<BB * 2, LT, 0, stream>>>(keys, 1, TILE);      // 4 runs -> 2
    merge_topk_kernel<<<BB * 1, LT, 0, stream>>>(keys, 0, 2 * TILE);  // 2 runs -> 1
    gather_kernel<<<(BB * KK) / (RPG * 4), 256, 0, stream>>>(h, keys, out);
}